// Round 1
// baseline (247.077 us; speedup 1.0000x reference)
//
#include <hip/hip_runtime.h>

typedef unsigned short u16;
typedef unsigned int   u32;
typedef __attribute__((ext_vector_type(8))) short bf16x8;
typedef __attribute__((ext_vector_type(4))) float f32x4;

#define EPSF 1e-15f

// Per-row layout inside the x input buffer (f32, row stride 128 floats = 512 B):
//   [0,32)   st as bf16 (64 values packed into 32 u32 words) [k_a; read by k_c]
//            -> after k_d2, [0,8) is REUSED for s2 packed bf16 (16 vals) [read by k_e]
//   [32,64)  y = adjn_unscaled@x1 accumulator (zeroed k_a, atomics k_y)
//   [64,96)  x1
//   [96,112) slot 96 = original-degree accumulator (k_c -> k_y)
//   112      q1 = ||st_row||^2 (bf16-rounded st)
//   113      d2 = rowsum(adjn_unscaled)
//   [114,128) spare -> batch accumulators, rows b*1024 + a/14
// Accumulator a per batch: 0 Dsum, 1 T1, 2 Tq1, 3 Pg, 4 Q2, 5 T2,
//   6..518 outm (k*32+h), 518..774 oam (k*16+l) UNSCALED, 774..1030 ssm,
//   1030..1034 per-batch loss scalars (ct, o1, mc, o2) from k_f1 -> k_f2.
// d_ws: an matrix (unscaled adj_new) as packed bf16, [b][n][m/2] u32, 32 MB.
__device__ __forceinline__ float* accp(float* xb, int b, int a) {
    return xb + (size_t)(b*1024 + a/14)*128 + 114 + (a % 14);
}

__device__ __forceinline__ float bf2f(u16 u) {
    union { u32 i; float f; } v; v.i = ((u32)u) << 16; return v.f;
}
__device__ __forceinline__ u16 f2bf(float f) {
    union { u32 i; float f; } v; v.f = f;
    u32 r = v.i + 0x7fffu + ((v.i >> 16) & 1u);
    return (u16)(r >> 16);
}

// ---------------- Kernel A: x1 = x@W1+b1 ; st = tanh(x1@Wp1+bp1) stored bf16;
// q1 = ||st_bf16||^2 ; zero y + degree + d2 + accumulator spares.
// 16 rows per block (4x weight-staging amortization vs old 4-row blocks).
__global__ __launch_bounds__(256) void k_a(float* xb,
        const float* __restrict__ W1, const float* __restrict__ b1,
        const float* __restrict__ Wp1, const float* __restrict__ bp1)
{
    __shared__ float W1s[128*32];
    __shared__ float Wp1s[32*64];
    __shared__ float xs[16][128];
    __shared__ float x1s[16][32];
    int tid = threadIdx.x;
    for (int i = tid; i < 1024; i += 256)
        *(float4*)&W1s[i*4] = *(const float4*)&W1[i*4];
    for (int i = tid; i < 512; i += 256)
        *(float4*)&Wp1s[i*4] = *(const float4*)&Wp1[i*4];
    int rbase = blockIdx.x*16;
    for (int e = tid; e < 512; e += 256) {
        int rr = e >> 5, c = e & 31;
        *(float4*)&xs[rr][c*4] = *(const float4*)&xb[(size_t)(rbase + rr)*128 + c*4];
    }
    __syncthreads();
    int w = tid >> 6, l = tid & 63;
    #pragma unroll
    for (int i = 0; i < 4; ++i) {
        int rr = w*4 + i;
        float* xr = xb + (size_t)(rbase + rr)*128;
        if (l < 32) xr[32 + l] = 0.f;
        if (l == 33) xr[96] = 0.f;
        if (l < 15) xr[113 + l] = 0.f;
        if (l < 32) {
            float acc = b1[l];
            for (int f = 0; f < 128; ++f) acc += xs[rr][f]*W1s[f*32 + l];
            x1s[rr][l] = acc;
        }
    }
    __syncthreads();
    #pragma unroll
    for (int i = 0; i < 4; ++i) {
        int rr = w*4 + i;
        float* xr = xb + (size_t)(rbase + rr)*128;
        if (l < 32) xr[64 + l] = x1s[rr][l];
        float acc = bp1[l];
        for (int h = 0; h < 32; ++h) acc += x1s[rr][h]*Wp1s[h*64 + l];
        float sv = tanhf(acc);
        u32 me = (u32)f2bf(sv);
        u32 nb = __shfl_down(me, 1);
        if (!(l & 1)) ((u32*)xr)[l >> 1] = me | (nb << 16);
        float svr = bf2f((u16)me);
        float qv = svr*svr;
        for (int off = 32; off; off >>= 1) qv += __shfl_down(qv, off);
        if (l == 0) xr[112] = qv;
    }
}

// ---------------- Kernel C (MFMA): ONE (ti,tj) 64x64 tile per block, grid (16,16,16).
// Latency-bound before (Occ 21%, VALU 17%): flattened, y-pass moved to k_y,
// float4 staging, adj loads issued at block entry, 2 barriers, VGPR-slim.
// G = st stT via mfma; an = sqrt(max(qi+qj-2G,0))*adj -> bf16 to anb (d_ws).
// Fused: degree rowsum->96, d2 rowsum->113, Pg/Q2 batch scalars.
__global__ __launch_bounds__(256, 6) void k_c(const float* __restrict__ adj, float* xb,
                                              u32* __restrict__ anb)
{
    __shared__ __align__(16) u16 BufA[64*72];  // st_ti
    __shared__ __align__(16) u16 BufB[64*72];  // st_tj
    __shared__ __align__(16) float qAs[64], qBs[64];
    __shared__ float pw[2][4];
    int tid = threadIdx.x;
    int tj = blockIdx.x, ti = blockIdx.y, b = blockIdx.z;
    int w = tid >> 6, lane = tid & 63;
    int q = lane >> 4, c16 = lane & 15;
    int rloc = w*16 + c16;
    size_t rowg = (size_t)(b*1024 + ti*64 + rloc);
    // adj loads first: ~2 barriers + staging of prefetch distance before use
    float4 a4s[4];
    #pragma unroll
    for (int t = 0; t < 4; ++t)
        a4s[t] = *(const float4*)&adj[rowg*1024 + tj*64 + t*16 + q*4];
    const u32* xu = (const u32*)xb;
    for (int e = tid; e < 512; e += 256) {
        int n = e >> 3, c = e & 7;
        *(float4*)&BufA[n*72 + c*8] = *(const float4*)&xu[(size_t)(b*1024 + ti*64 + n)*128 + c*4];
    }
    for (int e = tid; e < 512; e += 256) {
        int n = e >> 3, c = e & 7;
        *(float4*)&BufB[n*72 + c*8] = *(const float4*)&xu[(size_t)(b*1024 + tj*64 + n)*128 + c*4];
    }
    if (tid < 64) qAs[tid] = xb[(size_t)(b*1024 + ti*64 + tid)*128 + 112];
    else if (tid < 128) qBs[tid - 64] = xb[(size_t)(b*1024 + tj*64 + (tid - 64))*128 + 112];
    __syncthreads();
    bf16x8 bfr0 = *(const bf16x8*)&BufA[rloc*72 + q*8];
    bf16x8 bfr1 = *(const bf16x8*)&BufA[rloc*72 + 32 + q*8];
    float qa = qAs[rloc];
    f32x4 g[4];
    #pragma unroll
    for (int t = 0; t < 4; ++t) {
        bf16x8 af0 = *(const bf16x8*)&BufB[(t*16 + c16)*72 + q*8];
        bf16x8 af1 = *(const bf16x8*)&BufB[(t*16 + c16)*72 + 32 + q*8];
        f32x4 gg = {0.f, 0.f, 0.f, 0.f};
        gg = __builtin_amdgcn_mfma_f32_16x16x32_bf16(af0, bfr0, gg, 0, 0, 0);
        gg = __builtin_amdgcn_mfma_f32_16x16x32_bf16(af1, bfr1, gg, 0, 0, 0);
        g[t] = gg;
    }
    float dsum = 0.f, rsum = 0.f, Pt = 0.f, Qt = 0.f;
    #pragma unroll
    for (int t = 0; t < 4; ++t) {
        float4 a4 = a4s[t];
        float4 qb4 = *(const float4*)&qBs[t*16 + q*4];
        float av[4] = {a4.x, a4.y, a4.z, a4.w};
        float qb[4] = {qb4.x, qb4.y, qb4.z, qb4.w};
        float o[4];
        #pragma unroll
        for (int rg = 0; rg < 4; ++rg) {
            float d2v = qa + qb[rg] - 2.f*g[t][rg];
            float dist = sqrtf(fmaxf(d2v, 0.f));
            o[rg] = dist * av[rg];
            dsum += av[rg];
            rsum += o[rg];
            Pt += av[rg]*g[t][rg];
            Qt += g[t][rg]*g[t][rg];
        }
        u32 p0 = (u32)f2bf(o[0]) | ((u32)f2bf(o[1]) << 16);
        u32 p1 = (u32)f2bf(o[2]) | ((u32)f2bf(o[3]) << 16);
        *(uint2*)&anb[rowg*512 + tj*32 + t*8 + q*2] = make_uint2(p0, p1);
    }
    rsum += __shfl_xor(rsum, 16); rsum += __shfl_xor(rsum, 32);
    dsum += __shfl_xor(dsum, 16); dsum += __shfl_xor(dsum, 32);
    if (q == 0) {
        atomicAdd(&xb[rowg*128 + 96],  dsum);
        atomicAdd(&xb[rowg*128 + 113], rsum);
    }
    for (int off = 32; off; off >>= 1) { Pt += __shfl_down(Pt, off); Qt += __shfl_down(Qt, off); }
    if (lane == 0) { pw[0][w] = Pt; pw[1][w] = Qt; }
    __syncthreads();
    if (tid == 0) {
        atomicAdd(accp(xb,b,3), pw[0][0]+pw[0][1]+pw[0][2]+pw[0][3]);
        atomicAdd(accp(xb,b,4), pw[1][0]+pw[1][1]+pw[1][2]+pw[1][3]);
    }
}

// ---------------- Kernel Y (MFMA): y = an@x1, transplanted from old k_c's fused pass
// (same fragment mapping + k-chunk order -> bit-identical partials, atomic-accumulated
// over the same 4 x 256-column partitions). Grid (4 kq, 16 ni, 16 b).
// kq==0 blocks also fold old k_t: per-batch Dsum, T1 = sum d*q1, Tq1 = sum q1.
__global__ __launch_bounds__(256) void k_y(const u32* __restrict__ anb, float* xb)
{
    __shared__ __align__(16) u16 X[32][264];  // x1T bf16 slice [h][m], padded (2-way free)
    int tid = threadIdx.x;
    int kq = blockIdx.x, ni = blockIdx.y, b = blockIdx.z;
    int w = tid >> 6, lane = tid & 63;
    int q = lane >> 4, c16 = lane & 15;
    int rloc = w*16 + c16;
    size_t rowg = (size_t)(b*1024 + ni*64 + rloc);
    // A-fragments: issue all 8 k-step loads up front (L3-resident anb), consume post-barrier
    bf16x8 afv[8];
    #pragma unroll
    for (int ks = 0; ks < 8; ++ks)
        afv[ks] = *(const bf16x8*)&anb[rowg*512 + kq*128 + ks*16 + q*4];
    // stage x1T bf16: m in [kq*256,+256), h in [0,32)
    for (int e = tid; e < 2048; e += 256) {
        int m = e >> 3, hq = e & 7;
        const float4 v = *(const float4*)&xb[(size_t)(b*1024 + kq*256 + m)*128 + 64 + hq*4];
        X[hq*4 + 0][m] = f2bf(v.x);
        X[hq*4 + 1][m] = f2bf(v.y);
        X[hq*4 + 2][m] = f2bf(v.z);
        X[hq*4 + 3][m] = f2bf(v.w);
    }
    __syncthreads();
    f32x4 acc0 = {0.f,0.f,0.f,0.f}, acc1 = {0.f,0.f,0.f,0.f};
    #pragma unroll
    for (int ks = 0; ks < 8; ++ks) {
        bf16x8 b0 = *(const bf16x8*)&X[c16][ks*32 + q*8];
        bf16x8 b1v = *(const bf16x8*)&X[c16 + 16][ks*32 + q*8];
        acc0 = __builtin_amdgcn_mfma_f32_16x16x32_bf16(afv[ks], b0,  acc0, 0, 0, 0);
        acc1 = __builtin_amdgcn_mfma_f32_16x16x32_bf16(afv[ks], b1v, acc1, 0, 0, 0);
    }
    #pragma unroll
    for (int rg = 0; rg < 4; ++rg) {
        size_t orow = (size_t)(b*1024 + ni*64 + w*16 + q*4 + rg)*128;
        atomicAdd(&xb[orow + 32 + c16], acc0[rg]);
        atomicAdd(&xb[orow + 48 + c16], acc1[rg]);
    }
    if (kq == 0 && tid < 64) {
        const float* xr = xb + (size_t)(b*1024 + ni*64 + tid)*128;
        float d = xr[96], qv = xr[112];
        float t0 = d, t1 = d*qv, t2 = qv;
        for (int off = 32; off; off >>= 1) {
            t0 += __shfl_down(t0, off); t1 += __shfl_down(t1, off); t2 += __shfl_down(t2, off);
        }
        if (tid == 0) {
            atomicAdd(accp(xb,b,0), t0);
            atomicAdd(accp(xb,b,1), t1);
            atomicAdd(accp(xb,b,2), t2);
        }
    }
}

// ---------------- Kernel D2: 32 rows per block, grid (32,16).
// Now also packs s2 as bf16 into row slots [0,8) (st is dead) for k_e staging.
__global__ __launch_bounds__(256) void k_d2(float* xb,
        const float* __restrict__ Wrel1, const float* __restrict__ brel1,
        const float* __restrict__ Wroot1,
        const float* __restrict__ Wp2, const float* __restrict__ bp2)
{
    __shared__ float ys[32*34];
    __shared__ float x1n[32*34];
    __shared__ float x2s[32*34];
    __shared__ float s2s[32*17];
    __shared__ float Wr[1024], Wo[1024], Wp[512];
    int tid = threadIdx.x;
    int tq = blockIdx.x, b = blockIdx.y;
    int rbase = b*1024 + tq*32;
    float invv = 1.f / (*accp(xb,b,0) + 1024.f*EPSF);
    for (int i = tid; i < 1024; i += 256) { Wr[i] = Wrel1[i]; Wo[i] = Wroot1[i]; }
    for (int i = tid; i < 512; i += 256) Wp[i] = Wp2[i];
    for (int e = tid; e < 1024; e += 256) {
        int r = e >> 5, h = e & 31;
        const float* xr = xb + (size_t)(rbase + r)*128;
        ys[r*34 + h]  = xr[32 + h] * invv;
        x1n[r*34 + h] = xr[64 + h];
    }
    __syncthreads();
    {
        int h = tid & 31, tg = tid >> 5;
        float brl = brel1[h];
        #pragma unroll
        for (int i = 0; i < 4; ++i) {
            int r = tg + 8*i;
            float v = brl;
            for (int j = 0; j < 32; ++j)
                v += ys[r*34 + j]*Wr[j*32 + h] + x1n[r*34 + j]*Wo[j*32 + h];
            x2s[r*34 + h] = v;
        }
    }
    __syncthreads();
    if (tid < 64) {
        int r = tid & 31;
        float lg[16];
        float mx = -1e30f;
        #pragma unroll
        for (int k = 0; k < 16; ++k) {
            float v = bp2[k];
            for (int j = 0; j < 32; ++j) v += x2s[r*34 + j]*Wp[j*16 + k];
            lg[k] = v; mx = fmaxf(mx, v);
        }
        float sum = 0.f;
        #pragma unroll
        for (int k = 0; k < 16; ++k) { lg[k] = expf(lg[k] - mx); sum += lg[k]; }
        float inv = 1.f/sum, q2v = 0.f;
        u32 pk[8];
        #pragma unroll
        for (int k = 0; k < 16; ++k) {
            float sv = lg[k]*inv;
            s2s[r*17 + k] = sv;
            u32 bfv = (u32)f2bf(sv);
            if (k & 1) pk[k>>1] |= bfv << 16; else pk[k>>1] = bfv;
            q2v += sv*sv;
        }
        if (tid < 32) {
            u32* xp = (u32*)(xb + (size_t)(rbase + r)*128);
            #pragma unroll
            for (int i2 = 0; i2 < 8; ++i2) xp[i2] = pk[i2];
        }
        float denp = (xb[(size_t)(rbase + r)*128 + 113]*invv + EPSF)*q2v;
        if (tid >= 32) denp = 0.f;
        for (int off = 32; off; off >>= 1) denp += __shfl_down(denp, off);
        if (tid == 0) atomicAdd(accp(xb,b,5), denp);
    }
    __syncthreads();
    {
        int k = tid >> 4, l = tid & 15;
        float s = 0.f;
        for (int r = 0; r < 32; ++r) s += s2s[r*17 + k]*s2s[r*17 + l];
        atomicAdd(accp(xb,b,774 + tid), s);
    }
    for (int e = tid; e < 512; e += 256) {
        int k = e >> 5, h = e & 31;
        float s = 0.f;
        for (int r = 0; r < 32; ++r) s += s2s[r*17 + k]*x2s[r*34 + h];
        atomicAdd(accp(xb,b,6 + k*32 + h), s);
    }
}

// ---------------- Kernel E (MFMA): block (miq,ni,b), 2 mi tiles, grid (8,16,16).
// Staging: BufA via float4; BufS/BufN from s2 PACKED bf16 (row slots [0,8)).
__global__ __launch_bounds__(256, 6) void k_e(const u32* __restrict__ anb, float* xb)
{
    __shared__ __align__(16) u16 BufA[64*72];
    __shared__ __align__(16) u16 BufS[16*72];
    __shared__ __align__(16) u16 BufN[16*72];
    __shared__ __align__(16) u16 zT[16*72];
    int tid = threadIdx.x;
    int miq = blockIdx.x, ni = blockIdx.y, b = blockIdx.z;
    const u32* xu = (const u32*)xb;
    for (int e = tid; e < 512; e += 256) {
        int node = e >> 3, lw = e & 7;
        u32 pp = xu[(size_t)(b*1024 + ni*64 + node)*128 + lw];
        BufN[(lw*2)*72 + node]     = (u16)pp;
        BufN[(lw*2 + 1)*72 + node] = (u16)(pp >> 16);
    }
    int w = tid >> 6, lane = tid & 63;
    int q = lane >> 4, c16 = lane & 15;
    int rloc = w*16 + c16;
    f32x4 zacc = {0.f, 0.f, 0.f, 0.f};
    #pragma unroll
    for (int mii = 0; mii < 2; ++mii) {
        int mi = miq*2 + mii;
        __syncthreads();
        for (int e = tid; e < 512; e += 256) {
            int n = e >> 3, c = e & 7;
            *(float4*)&BufA[n*72 + c*8] =
                *(const float4*)&anb[(size_t)(b*1024 + ni*64 + n)*512 + mi*32 + c*4];
        }
        for (int e = tid; e < 512; e += 256) {
            int node = e >> 3, lw = e & 7;
            u32 pp = xu[(size_t)(b*1024 + mi*64 + node)*128 + lw];
            BufS[(lw*2)*72 + node]     = (u16)pp;
            BufS[(lw*2 + 1)*72 + node] = (u16)(pp >> 16);
        }
        __syncthreads();
        bf16x8 ya0 = *(const bf16x8*)&BufA[rloc*72 + q*8];
        bf16x8 ya1 = *(const bf16x8*)&BufA[rloc*72 + 32 + q*8];
        bf16x8 yb0 = *(const bf16x8*)&BufS[c16*72 + q*8];
        bf16x8 yb1 = *(const bf16x8*)&BufS[c16*72 + 32 + q*8];
        zacc = __builtin_amdgcn_mfma_f32_16x16x32_bf16(ya0, yb0, zacc, 0, 0, 0);
        zacc = __builtin_amdgcn_mfma_f32_16x16x32_bf16(ya1, yb1, zacc, 0, 0, 0);
    }
    #pragma unroll
    for (int rg = 0; rg < 4; ++rg)
        zT[c16*72 + w*16 + q*4 + rg] = f2bf(zacc[rg]);
    __syncthreads();
    if (w == 0) {
        bf16x8 af0 = *(const bf16x8*)&BufN[c16*72 + q*8];
        bf16x8 af1 = *(const bf16x8*)&BufN[c16*72 + 32 + q*8];
        bf16x8 bz0 = *(const bf16x8*)&zT[c16*72 + q*8];
        bf16x8 bz1 = *(const bf16x8*)&zT[c16*72 + 32 + q*8];
        f32x4 oamv = {0.f, 0.f, 0.f, 0.f};
        oamv = __builtin_amdgcn_mfma_f32_16x16x32_bf16(af0, bz0, oamv, 0, 0, 0);
        oamv = __builtin_amdgcn_mfma_f32_16x16x32_bf16(af1, bz1, oamv, 0, 0, 0);
        #pragma unroll
        for (int rg = 0; rg < 4; ++rg)
            atomicAdd(accp(xb, b, 518 + (q*4 + rg)*16 + c16), oamv[rg]);
    }
}

// ---------------- Kernel F1: per-batch finalize (grid 16). Logits + per-batch loss scalars.
__global__ __launch_bounds__(256) void k_f1(float* xb,
        const float* __restrict__ Wrel2, const float* __restrict__ brel2,
        const float* __restrict__ Wroot2,
        const float* __restrict__ W_lin2, const float* __restrict__ b_lin2,
        const float* __restrict__ W_lin3, const float* __restrict__ b_lin3,
        float* __restrict__ outp)
{
    __shared__ float oam_s[256], ssm_s[256], outm_s[512];
    __shared__ float dks[16], csoa[16];
    __shared__ float cs0[32], cs1[32], xsum[32], x5[32], lgs[10];
    __shared__ float red[4];
    int b = blockIdx.x;
    int tid = threadIdx.x;
    float invv = 1.f / (*accp(xb,b,0) + 1024.f*EPSF);
    oam_s[tid] = *accp(xb,b,518 + tid) * invv;
    ssm_s[tid] = *accp(xb,b,774 + tid);
    for (int e = tid; e < 512; e += 256) outm_s[e] = *accp(xb,b,6 + e);
    __syncthreads();
    if (tid < 16) {
        float rsv = 0.f;
        for (int l = 0; l < 16; ++l) if (l != tid) rsv += oam_s[tid*16 + l];
        dks[tid] = sqrtf(fmaxf(rsv, 0.f) + EPSF) + EPSF;
    }
    {
        float v = ssm_s[tid];
        float p = v*v;
        for (int off = 32; off; off >>= 1) p += __shfl_down(p, off);
        if ((tid & 63) == 0) red[tid >> 6] = p;
    }
    __syncthreads();
    if (tid < 16) {
        float s = 0.f;
        for (int k2 = 0; k2 < 16; ++k2)
            if (k2 != tid) s += oam_s[k2*16 + tid] / dks[k2];
        csoa[tid] = s / dks[tid];
    }
    if (tid < 32) {
        float s0 = 0.f, s1 = 0.f;
        for (int l = 0; l < 16; ++l) {
            float ov = outm_s[l*32 + tid];
            s0 += ov;
            s1 += csoa[l] * ov;   // same wave as csoa writers; intra-wave order holds
        }
        cs0[tid] = s0; cs1[tid] = s1;
    }
    if (tid == 64) {
        float T1v  = *accp(xb,b,1);
        float Pgv  = *accp(xb,b,3);
        float Q2v  = *accp(xb,b,4);
        float Tq1v = *accp(xb,b,2);
        float T2v  = *accp(xb,b,5);
        *accp(xb,b,1030) = (T1v - Pgv) / (T1v + EPSF);
        *accp(xb,b,1031) = 65.f - 2.f*Tq1v/sqrtf(fmaxf(Q2v, 1e-30f));
        float tr2 = 0.f, trs = 0.f;
        for (int k2 = 0; k2 < 16; ++k2) { tr2 += oam_s[k2*17]; trs += ssm_s[k2*17]; }
        *accp(xb,b,1032) = -tr2 / T2v;
        float fr2 = red[0] + red[1] + red[2] + red[3];
        *accp(xb,b,1033) = sqrtf(fmaxf(2.f - trs/(2.f*sqrtf(fmaxf(fr2, 1e-30f))), 0.f));
    }
    __syncthreads();
    if (tid < 32) {
        float v = 16.f * brel2[tid];
        for (int j = 0; j < 32; ++j)
            v += cs1[j]*Wrel2[j*32 + tid] + cs0[j]*Wroot2[j*32 + tid];
        xsum[tid] = v;
    }
    __syncthreads();
    if (tid < 32) {
        float v = b_lin2[tid];
        for (int j = 0; j < 32; ++j) v += xsum[j]*W_lin2[j*32 + tid];
        x5[tid] = fmaxf(v, 0.f);
    }
    __syncthreads();
    if (tid < 10) {
        float v = b_lin3[tid];
        for (int j = 0; j < 32; ++j) v += x5[j]*W_lin3[j*10 + tid];
        lgs[tid] = v;
    }
    __syncthreads();
    if (tid < 10) {
        float mx = -1e30f;
        for (int t = 0; t < 10; ++t) mx = fmaxf(mx, lgs[t]);
        float sum = 0.f;
        for (int t = 0; t < 10; ++t) sum += expf(lgs[t] - mx);
        outp[b*10 + tid] = lgs[tid] - mx - logf(sum);
    }
}

// ---------------- Kernel F2: final scalar losses (1 block, 64 threads)
__global__ __launch_bounds__(64) void k_f2(float* xb, float* __restrict__ outp)
{
    int tid = threadIdx.x;
    int b2 = tid & 15, which = tid >> 4;
    float v = *accp(xb, b2, 1030 + which);
    for (int off = 1; off < 16; off <<= 1) v += __shfl_xor(v, off);
    float ct = __shfl(v, 0);
    float o1 = __shfl(v, 16);
    float mc = __shfl(v, 32);
    float o2 = __shfl(v, 48);
    if (tid == 0) {
        outp[160] = ct/16.f + sqrtf(fmaxf(o1, 0.f));
        outp[161] = mc/16.f + o2/16.f;
    }
}

extern "C" void kernel_launch(void* const* d_in, const int* in_sizes, int n_in,
                              void* d_out, int out_size, void* d_ws, size_t ws_size,
                              hipStream_t stream)
{
    float* xb        = (float*)d_in[0];   // x, reused as scratch (restored by harness)
    const float* adj = (const float*)d_in[1];   // READ-ONLY
    const float* W_lin1 = (const float*)d_in[3];
    const float* b_lin1 = (const float*)d_in[4];
    const float* W_pool1= (const float*)d_in[5];
    const float* b_pool1= (const float*)d_in[6];
    const float* W_pool2= (const float*)d_in[7];
    const float* b_pool2= (const float*)d_in[8];
    const float* Wrel1  = (const float*)d_in[9];
    const float* brel1  = (const float*)d_in[10];
    const float* Wroot1 = (const float*)d_in[11];
    const float* Wrel2  = (const float*)d_in[12];
    const float* brel2  = (const float*)d_in[13];
    const float* Wroot2 = (const float*)d_in[14];
    const float* W_lin2 = (const float*)d_in[15];
    const float* b_lin2 = (const float*)d_in[16];
    const float* W_lin3 = (const float*)d_in[17];
    const float* b_lin3 = (const float*)d_in[18];
    u32* anb = (u32*)d_ws;   // 32 MB, fully overwritten by k_c
    (void)ws_size; (void)in_sizes; (void)n_in; (void)out_size;

    k_a<<<dim3(1024),      dim3(256), 0, stream>>>(xb, W_lin1, b_lin1, W_pool1, b_pool1);
    k_c<<<dim3(16,16,16),  dim3(256), 0, stream>>>(adj, xb, anb);
    k_y<<<dim3(4,16,16),   dim3(256), 0, stream>>>(anb, xb);
    k_d2<<<dim3(32,16),    dim3(256), 0, stream>>>(xb, Wrel1, brel1, Wroot1,
                                                   W_pool2, b_pool2);
    k_e<<<dim3(8,16,16),   dim3(256), 0, stream>>>(anb, xb);
    k_f1<<<dim3(16),       dim3(256), 0, stream>>>(xb, Wrel2, brel2, Wroot2,
                                                   W_lin2, b_lin2, W_lin3, b_lin3,
                                                   (float*)d_out);
    k_f2<<<dim3(1),        dim3(64),  0, stream>>>(xb, (float*)d_out);
}

// Round 2
// 227.534 us; speedup vs baseline: 1.0859x; 1.0859x over previous
//
#include <hip/hip_runtime.h>

typedef unsigned short u16;
typedef unsigned int   u32;
typedef __attribute__((ext_vector_type(8))) short bf16x8;
typedef __attribute__((ext_vector_type(4))) float f32x4;

#define EPSF 1e-15f

// Per-row layout inside the x input buffer (f32, row stride 128 floats = 512 B):
//   [0,32)   st as bf16 (64 values packed into 32 u32 words) [k_a; read by k_c]
//            -> after k_d2, [0,8) is REUSED for s2 packed bf16 (16 vals) [read by k_e]
//   [32,64)  y = adjn_unscaled@x1 (PLAIN stores by k_y, no atomics)
//   [64,96)  x1
//   [96,112) slot 96 = original-degree accumulator (k_c -> k_y)
//   112      q1 = ||st_row||^2 (bf16-rounded st)
//   113      d2 = rowsum(adjn_unscaled)
//   [114,128) spare -> batch accumulators, rows b*1024 + a/14
// Accumulator a per batch: 0 Dsum, 1 T1, 2 Tq1, 3 Pg, 4 Q2, 5 T2,
//   6..518 outm (k*32+h), 518..774 oam (k*16+l) UNSCALED, 774..1030 ssm,
//   1030..1034 per-batch loss scalars (ct, o1, mc, o2), 1035 = k_f1 last-block counter.
// d_ws: an matrix (unscaled adj_new) as packed bf16, [b][n][m/2] u32, 32 MB.
__device__ __forceinline__ float* accp(float* xb, int b, int a) {
    return xb + (size_t)(b*1024 + a/14)*128 + 114 + (a % 14);
}

__device__ __forceinline__ float bf2f(u16 u) {
    union { u32 i; float f; } v; v.i = ((u32)u) << 16; return v.f;
}
__device__ __forceinline__ u16 f2bf(float f) {
    union { u32 i; float f; } v; v.f = f;
    u32 r = v.i + 0x7fffu + ((v.i >> 16) & 1u);
    return (u16)(r >> 16);
}

// ---------------- Kernel A: x1 = x@W1+b1 ; st = tanh(x1@Wp1+bp1) stored bf16;
// q1 = ||st_bf16||^2 ; zero degree + d2 + accumulator spares.
// GEMM1 now uses all 64 lanes (k-split halves + shfl combine).
__global__ __launch_bounds__(256) void k_a(float* xb,
        const float* __restrict__ W1, const float* __restrict__ b1,
        const float* __restrict__ Wp1, const float* __restrict__ bp1)
{
    __shared__ float W1s[128*32];
    __shared__ float Wp1s[32*64];
    __shared__ float xs[16][128];
    __shared__ float x1s[16][32];
    int tid = threadIdx.x;
    for (int i = tid; i < 1024; i += 256)
        *(float4*)&W1s[i*4] = *(const float4*)&W1[i*4];
    for (int i = tid; i < 512; i += 256)
        *(float4*)&Wp1s[i*4] = *(const float4*)&Wp1[i*4];
    int rbase = blockIdx.x*16;
    for (int e = tid; e < 512; e += 256) {
        int rr = e >> 5, c = e & 31;
        *(float4*)&xs[rr][c*4] = *(const float4*)&xb[(size_t)(rbase + rr)*128 + c*4];
    }
    __syncthreads();
    int w = tid >> 6, l = tid & 63;
    int col = l & 31, half = l >> 5;
    #pragma unroll
    for (int i = 0; i < 4; ++i) {
        int rr = w*4 + i;
        float* xr = xb + (size_t)(rbase + rr)*128;
        if (l == 33) xr[96] = 0.f;
        if (l < 15) xr[113 + l] = 0.f;
        float acc = half ? 0.f : b1[col];
        const float* xrow = &xs[rr][half*64];
        const float* wrow = &W1s[half*64*32 + col];
        for (int f = 0; f < 64; ++f) acc += xrow[f]*wrow[f*32];
        acc += __shfl_down(acc, 32);
        if (l < 32) x1s[rr][l] = acc;
    }
    __syncthreads();
    #pragma unroll
    for (int i = 0; i < 4; ++i) {
        int rr = w*4 + i;
        float* xr = xb + (size_t)(rbase + rr)*128;
        if (l < 32) xr[64 + l] = x1s[rr][l];
        float acc = bp1[l];
        for (int h = 0; h < 32; ++h) acc += x1s[rr][h]*Wp1s[h*64 + l];
        float sv = tanhf(acc);
        u32 me = (u32)f2bf(sv);
        u32 nb = __shfl_down(me, 1);
        if (!(l & 1)) ((u32*)xr)[l >> 1] = me | (nb << 16);
        float svr = bf2f((u16)me);
        float qv = svr*svr;
        for (int off = 32; off; off >>= 1) qv += __shfl_down(qv, off);
        if (l == 0) xr[112] = qv;
    }
}

// ---------------- Kernel C (MFMA): TWO tj tiles per block, grid (8,16,16).
// All 8 adj float4 loads issued at entry; both BufB tiles staged before the
// single barrier; epilogue reductions/atomics amortized over 128 cols.
__global__ __launch_bounds__(256, 5) void k_c(const float* __restrict__ adj, float* xb,
                                              u32* __restrict__ anb)
{
    __shared__ __align__(16) u16 BufA[64*72];     // st_ti
    __shared__ __align__(16) u16 BufB[2][64*72];  // st_tj (2 tiles)
    __shared__ __align__(16) float qAs[64], qBs[2][64];
    __shared__ float pw[2][4];
    int tid = threadIdx.x;
    int tjq = blockIdx.x, ti = blockIdx.y, b = blockIdx.z;
    int w = tid >> 6, lane = tid & 63;
    int q = lane >> 4, c16 = lane & 15;
    int rloc = w*16 + c16;
    size_t rowg = (size_t)(b*1024 + ti*64 + rloc);
    // adj loads first: max prefetch distance
    float4 a4s[2][4];
    #pragma unroll
    for (int tt = 0; tt < 2; ++tt)
        #pragma unroll
        for (int t = 0; t < 4; ++t)
            a4s[tt][t] = *(const float4*)&adj[rowg*1024 + (tjq*2 + tt)*64 + t*16 + q*4];
    const u32* xu = (const u32*)xb;
    for (int e = tid; e < 512; e += 256) {
        int n = e >> 3, c = e & 7;
        *(float4*)&BufA[n*72 + c*8] = *(const float4*)&xu[(size_t)(b*1024 + ti*64 + n)*128 + c*4];
    }
    for (int e = tid; e < 1024; e += 256) {
        int n2 = e >> 3, c = e & 7;
        int tt = n2 >> 6, n = n2 & 63;
        *(float4*)&BufB[tt][n*72 + c*8] =
            *(const float4*)&xu[(size_t)(b*1024 + (tjq*2 + tt)*64 + n)*128 + c*4];
    }
    if (tid < 64) qAs[tid] = xb[(size_t)(b*1024 + ti*64 + tid)*128 + 112];
    else if (tid < 192) {
        int t2 = tid - 64;
        qBs[t2 >> 6][t2 & 63] =
            xb[(size_t)(b*1024 + (tjq*2 + (t2 >> 6))*64 + (t2 & 63))*128 + 112];
    }
    __syncthreads();
    bf16x8 bfr0 = *(const bf16x8*)&BufA[rloc*72 + q*8];
    bf16x8 bfr1 = *(const bf16x8*)&BufA[rloc*72 + 32 + q*8];
    float qa = qAs[rloc];
    float dsum = 0.f, rsum = 0.f, Pt = 0.f, Qt = 0.f;
    #pragma unroll
    for (int tt = 0; tt < 2; ++tt) {
        f32x4 g[4];
        #pragma unroll
        for (int t = 0; t < 4; ++t) {
            bf16x8 af0 = *(const bf16x8*)&BufB[tt][(t*16 + c16)*72 + q*8];
            bf16x8 af1 = *(const bf16x8*)&BufB[tt][(t*16 + c16)*72 + 32 + q*8];
            f32x4 gg = {0.f, 0.f, 0.f, 0.f};
            gg = __builtin_amdgcn_mfma_f32_16x16x32_bf16(af0, bfr0, gg, 0, 0, 0);
            gg = __builtin_amdgcn_mfma_f32_16x16x32_bf16(af1, bfr1, gg, 0, 0, 0);
            g[t] = gg;
        }
        #pragma unroll
        for (int t = 0; t < 4; ++t) {
            float4 a4 = a4s[tt][t];
            float4 qb4 = *(const float4*)&qBs[tt][t*16 + q*4];
            float av[4] = {a4.x, a4.y, a4.z, a4.w};
            float qb[4] = {qb4.x, qb4.y, qb4.z, qb4.w};
            float o[4];
            #pragma unroll
            for (int rg = 0; rg < 4; ++rg) {
                float d2v = qa + qb[rg] - 2.f*g[t][rg];
                float dist = sqrtf(fmaxf(d2v, 0.f));
                o[rg] = dist * av[rg];
                dsum += av[rg];
                rsum += o[rg];
                Pt += av[rg]*g[t][rg];
                Qt += g[t][rg]*g[t][rg];
            }
            u32 p0 = (u32)f2bf(o[0]) | ((u32)f2bf(o[1]) << 16);
            u32 p1 = (u32)f2bf(o[2]) | ((u32)f2bf(o[3]) << 16);
            *(uint2*)&anb[rowg*512 + (tjq*2 + tt)*32 + t*8 + q*2] = make_uint2(p0, p1);
        }
    }
    rsum += __shfl_xor(rsum, 16); rsum += __shfl_xor(rsum, 32);
    dsum += __shfl_xor(dsum, 16); dsum += __shfl_xor(dsum, 32);
    if (q == 0) {
        atomicAdd(&xb[rowg*128 + 96],  dsum);
        atomicAdd(&xb[rowg*128 + 113], rsum);
    }
    for (int off = 32; off; off >>= 1) { Pt += __shfl_down(Pt, off); Qt += __shfl_down(Qt, off); }
    if (lane == 0) { pw[0][w] = Pt; pw[1][w] = Qt; }
    __syncthreads();
    if (tid == 0) {
        atomicAdd(accp(xb,b,3), pw[0][0]+pw[0][1]+pw[0][2]+pw[0][3]);
        atomicAdd(accp(xb,b,4), pw[1][0]+pw[1][1]+pw[1][2]+pw[1][3]);
    }
}

// ---------------- Kernel Y (MFMA): y = an@x1 with FULL K per block — no atomics.
// Grid (16 ni, 16 b), 256 threads. x1T bf16 staged once in 66 KB LDS; an
// fragments streamed straight from L3-resident anb inside the K loop.
// Also folds old k_t: per-batch Dsum, T1 = sum d*q1, Tq1 = sum q1.
__global__ __launch_bounds__(256) void k_y(const u32* __restrict__ anb, float* xb)
{
    __shared__ __align__(16) u16 X[32][1032];  // x1T bf16 [h][m], pad 8 (2-way free)
    int tid = threadIdx.x;
    int ni = blockIdx.x, b = blockIdx.y;
    int w = tid >> 6, lane = tid & 63;
    int q = lane >> 4, c16 = lane & 15;
    int rloc = w*16 + c16;
    size_t rowg = (size_t)(b*1024 + ni*64 + rloc);
    for (int e = tid; e < 8192; e += 256) {
        int m = e >> 3, hq = e & 7;
        const float4 v = *(const float4*)&xb[(size_t)(b*1024 + m)*128 + 64 + hq*4];
        X[hq*4 + 0][m] = f2bf(v.x);
        X[hq*4 + 1][m] = f2bf(v.y);
        X[hq*4 + 2][m] = f2bf(v.z);
        X[hq*4 + 3][m] = f2bf(v.w);
    }
    __syncthreads();
    f32x4 acc0 = {0.f,0.f,0.f,0.f}, acc1 = {0.f,0.f,0.f,0.f};
    #pragma unroll 8
    for (int ks = 0; ks < 32; ++ks) {
        bf16x8 af  = *(const bf16x8*)&anb[rowg*512 + ks*16 + q*4];
        bf16x8 b0  = *(const bf16x8*)&X[c16][ks*32 + q*8];
        bf16x8 b1v = *(const bf16x8*)&X[c16 + 16][ks*32 + q*8];
        acc0 = __builtin_amdgcn_mfma_f32_16x16x32_bf16(af, b0,  acc0, 0, 0, 0);
        acc1 = __builtin_amdgcn_mfma_f32_16x16x32_bf16(af, b1v, acc1, 0, 0, 0);
    }
    #pragma unroll
    for (int rg = 0; rg < 4; ++rg) {
        size_t orow = (size_t)(b*1024 + ni*64 + w*16 + q*4 + rg)*128;
        xb[orow + 32 + c16] = acc0[rg];
        xb[orow + 48 + c16] = acc1[rg];
    }
    if (tid < 64) {
        const float* xr = xb + (size_t)(b*1024 + ni*64 + tid)*128;
        float d = xr[96], qv = xr[112];
        float t0 = d, t1 = d*qv, t2 = qv;
        for (int off = 32; off; off >>= 1) {
            t0 += __shfl_down(t0, off); t1 += __shfl_down(t1, off); t2 += __shfl_down(t2, off);
        }
        if (tid == 0) {
            atomicAdd(accp(xb,b,0), t0);
            atomicAdd(accp(xb,b,1), t1);
            atomicAdd(accp(xb,b,2), t2);
        }
    }
}

// ---------------- Kernel D2: 32 rows per block, grid (32,16).
// Packs s2 as bf16 into row slots [0,8) (st is dead) for k_e staging.
__global__ __launch_bounds__(256) void k_d2(float* xb,
        const float* __restrict__ Wrel1, const float* __restrict__ brel1,
        const float* __restrict__ Wroot1,
        const float* __restrict__ Wp2, const float* __restrict__ bp2)
{
    __shared__ float ys[32*34];
    __shared__ float x1n[32*34];
    __shared__ float x2s[32*34];
    __shared__ float s2s[32*17];
    __shared__ float Wr[1024], Wo[1024], Wp[512];
    int tid = threadIdx.x;
    int tq = blockIdx.x, b = blockIdx.y;
    int rbase = b*1024 + tq*32;
    float invv = 1.f / (*accp(xb,b,0) + 1024.f*EPSF);
    for (int i = tid; i < 1024; i += 256) { Wr[i] = Wrel1[i]; Wo[i] = Wroot1[i]; }
    for (int i = tid; i < 512; i += 256) Wp[i] = Wp2[i];
    for (int e = tid; e < 1024; e += 256) {
        int r = e >> 5, h = e & 31;
        const float* xr = xb + (size_t)(rbase + r)*128;
        ys[r*34 + h]  = xr[32 + h] * invv;
        x1n[r*34 + h] = xr[64 + h];
    }
    __syncthreads();
    {
        int h = tid & 31, tg = tid >> 5;
        float brl = brel1[h];
        #pragma unroll
        for (int i = 0; i < 4; ++i) {
            int r = tg + 8*i;
            float v = brl;
            for (int j = 0; j < 32; ++j)
                v += ys[r*34 + j]*Wr[j*32 + h] + x1n[r*34 + j]*Wo[j*32 + h];
            x2s[r*34 + h] = v;
        }
    }
    __syncthreads();
    if (tid < 64) {
        int r = tid & 31;
        float lg[16];
        float mx = -1e30f;
        #pragma unroll
        for (int k = 0; k < 16; ++k) {
            float v = bp2[k];
            for (int j = 0; j < 32; ++j) v += x2s[r*34 + j]*Wp[j*16 + k];
            lg[k] = v; mx = fmaxf(mx, v);
        }
        float sum = 0.f;
        #pragma unroll
        for (int k = 0; k < 16; ++k) { lg[k] = expf(lg[k] - mx); sum += lg[k]; }
        float inv = 1.f/sum, q2v = 0.f;
        u32 pk[8];
        #pragma unroll
        for (int k = 0; k < 16; ++k) {
            float sv = lg[k]*inv;
            s2s[r*17 + k] = sv;
            u32 bfv = (u32)f2bf(sv);
            if (k & 1) pk[k>>1] |= bfv << 16; else pk[k>>1] = bfv;
            q2v += sv*sv;
        }
        if (tid < 32) {
            u32* xp = (u32*)(xb + (size_t)(rbase + r)*128);
            #pragma unroll
            for (int i2 = 0; i2 < 8; ++i2) xp[i2] = pk[i2];
        }
        float denp = (xb[(size_t)(rbase + r)*128 + 113]*invv + EPSF)*q2v;
        if (tid >= 32) denp = 0.f;
        for (int off = 32; off; off >>= 1) denp += __shfl_down(denp, off);
        if (tid == 0) atomicAdd(accp(xb,b,5), denp);
    }
    __syncthreads();
    {
        int k = tid >> 4, l = tid & 15;
        float s = 0.f;
        for (int r = 0; r < 32; ++r) s += s2s[r*17 + k]*s2s[r*17 + l];
        atomicAdd(accp(xb,b,774 + tid), s);
    }
    for (int e = tid; e < 512; e += 256) {
        int k = e >> 5, h = e & 31;
        float s = 0.f;
        for (int r = 0; r < 32; ++r) s += s2s[r*17 + k]*x2s[r*34 + h];
        atomicAdd(accp(xb,b,6 + k*32 + h), s);
    }
}

// ---------------- Kernel E (MFMA): block (miq,ni,b), 2 mi tiles, grid (8,16,16).
// Staging: BufA via float4; BufS/BufN from s2 PACKED bf16 (row slots [0,8)).
__global__ __launch_bounds__(256, 6) void k_e(const u32* __restrict__ anb, float* xb)
{
    __shared__ __align__(16) u16 BufA[64*72];
    __shared__ __align__(16) u16 BufS[16*72];
    __shared__ __align__(16) u16 BufN[16*72];
    __shared__ __align__(16) u16 zT[16*72];
    int tid = threadIdx.x;
    int miq = blockIdx.x, ni = blockIdx.y, b = blockIdx.z;
    const u32* xu = (const u32*)xb;
    for (int e = tid; e < 512; e += 256) {
        int node = e >> 3, lw = e & 7;
        u32 pp = xu[(size_t)(b*1024 + ni*64 + node)*128 + lw];
        BufN[(lw*2)*72 + node]     = (u16)pp;
        BufN[(lw*2 + 1)*72 + node] = (u16)(pp >> 16);
    }
    int w = tid >> 6, lane = tid & 63;
    int q = lane >> 4, c16 = lane & 15;
    int rloc = w*16 + c16;
    f32x4 zacc = {0.f, 0.f, 0.f, 0.f};
    #pragma unroll
    for (int mii = 0; mii < 2; ++mii) {
        int mi = miq*2 + mii;
        __syncthreads();
        for (int e = tid; e < 512; e += 256) {
            int n = e >> 3, c = e & 7;
            *(float4*)&BufA[n*72 + c*8] =
                *(const float4*)&anb[(size_t)(b*1024 + ni*64 + n)*512 + mi*32 + c*4];
        }
        for (int e = tid; e < 512; e += 256) {
            int node = e >> 3, lw = e & 7;
            u32 pp = xu[(size_t)(b*1024 + mi*64 + node)*128 + lw];
            BufS[(lw*2)*72 + node]     = (u16)pp;
            BufS[(lw*2 + 1)*72 + node] = (u16)(pp >> 16);
        }
        __syncthreads();
        bf16x8 ya0 = *(const bf16x8*)&BufA[rloc*72 + q*8];
        bf16x8 ya1 = *(const bf16x8*)&BufA[rloc*72 + 32 + q*8];
        bf16x8 yb0 = *(const bf16x8*)&BufS[c16*72 + q*8];
        bf16x8 yb1 = *(const bf16x8*)&BufS[c16*72 + 32 + q*8];
        zacc = __builtin_amdgcn_mfma_f32_16x16x32_bf16(ya0, yb0, zacc, 0, 0, 0);
        zacc = __builtin_amdgcn_mfma_f32_16x16x32_bf16(ya1, yb1, zacc, 0, 0, 0);
    }
    #pragma unroll
    for (int rg = 0; rg < 4; ++rg)
        zT[c16*72 + w*16 + q*4 + rg] = f2bf(zacc[rg]);
    __syncthreads();
    if (w == 0) {
        bf16x8 af0 = *(const bf16x8*)&BufN[c16*72 + q*8];
        bf16x8 af1 = *(const bf16x8*)&BufN[c16*72 + 32 + q*8];
        bf16x8 bz0 = *(const bf16x8*)&zT[c16*72 + q*8];
        bf16x8 bz1 = *(const bf16x8*)&zT[c16*72 + 32 + q*8];
        f32x4 oamv = {0.f, 0.f, 0.f, 0.f};
        oamv = __builtin_amdgcn_mfma_f32_16x16x32_bf16(af0, bz0, oamv, 0, 0, 0);
        oamv = __builtin_amdgcn_mfma_f32_16x16x32_bf16(af1, bz1, oamv, 0, 0, 0);
        #pragma unroll
        for (int rg = 0; rg < 4; ++rg)
            atomicAdd(accp(xb, b, 518 + (q*4 + rg)*16 + c16), oamv[rg]);
    }
}

// ---------------- Kernel F1: per-batch finalize (grid 16). Logits + per-batch loss
// scalars. Last block to finish (device atomic counter) also does old k_f2's work.
__global__ __launch_bounds__(256) void k_f1(float* xb,
        const float* __restrict__ Wrel2, const float* __restrict__ brel2,
        const float* __restrict__ Wroot2,
        const float* __restrict__ W_lin2, const float* __restrict__ b_lin2,
        const float* __restrict__ W_lin3, const float* __restrict__ b_lin3,
        float* __restrict__ outp)
{
    __shared__ float oam_s[256], ssm_s[256], outm_s[512];
    __shared__ float dks[16], csoa[16];
    __shared__ float cs0[32], cs1[32], xsum[32], x5[32], lgs[10];
    __shared__ float red[4];
    __shared__ int isLast;
    int b = blockIdx.x;
    int tid = threadIdx.x;
    float invv = 1.f / (*accp(xb,b,0) + 1024.f*EPSF);
    oam_s[tid] = *accp(xb,b,518 + tid) * invv;
    ssm_s[tid] = *accp(xb,b,774 + tid);
    for (int e = tid; e < 512; e += 256) outm_s[e] = *accp(xb,b,6 + e);
    __syncthreads();
    if (tid < 16) {
        float rsv = 0.f;
        for (int l = 0; l < 16; ++l) if (l != tid) rsv += oam_s[tid*16 + l];
        dks[tid] = sqrtf(fmaxf(rsv, 0.f) + EPSF) + EPSF;
    }
    {
        float v = ssm_s[tid];
        float p = v*v;
        for (int off = 32; off; off >>= 1) p += __shfl_down(p, off);
        if ((tid & 63) == 0) red[tid >> 6] = p;
    }
    __syncthreads();
    if (tid < 16) {
        float s = 0.f;
        for (int k2 = 0; k2 < 16; ++k2)
            if (k2 != tid) s += oam_s[k2*16 + tid] / dks[k2];
        csoa[tid] = s / dks[tid];
    }
    if (tid < 32) {
        float s0 = 0.f, s1 = 0.f;
        for (int l = 0; l < 16; ++l) {
            float ov = outm_s[l*32 + tid];
            s0 += ov;
            s1 += csoa[l] * ov;   // same wave as csoa writers; intra-wave order holds
        }
        cs0[tid] = s0; cs1[tid] = s1;
    }
    if (tid == 64) {
        float T1v  = *accp(xb,b,1);
        float Pgv  = *accp(xb,b,3);
        float Q2v  = *accp(xb,b,4);
        float Tq1v = *accp(xb,b,2);
        float T2v  = *accp(xb,b,5);
        float tr2 = 0.f, trs = 0.f;
        for (int k2 = 0; k2 < 16; ++k2) { tr2 += oam_s[k2*17]; trs += ssm_s[k2*17]; }
        float fr2 = red[0] + red[1] + red[2] + red[3];
        // agent-scope atomic stores: visible cross-XCD to the last block
        __hip_atomic_store(accp(xb,b,1030), (T1v - Pgv) / (T1v + EPSF),
                           __ATOMIC_RELAXED, __HIP_MEMORY_SCOPE_AGENT);
        __hip_atomic_store(accp(xb,b,1031), 65.f - 2.f*Tq1v/sqrtf(fmaxf(Q2v, 1e-30f)),
                           __ATOMIC_RELAXED, __HIP_MEMORY_SCOPE_AGENT);
        __hip_atomic_store(accp(xb,b,1032), -tr2 / T2v,
                           __ATOMIC_RELAXED, __HIP_MEMORY_SCOPE_AGENT);
        __hip_atomic_store(accp(xb,b,1033),
                           sqrtf(fmaxf(2.f - trs/(2.f*sqrtf(fmaxf(fr2, 1e-30f))), 0.f)),
                           __ATOMIC_RELAXED, __HIP_MEMORY_SCOPE_AGENT);
    }
    __syncthreads();
    if (tid < 32) {
        float v = 16.f * brel2[tid];
        for (int j = 0; j < 32; ++j)
            v += cs1[j]*Wrel2[j*32 + tid] + cs0[j]*Wroot2[j*32 + tid];
        xsum[tid] = v;
    }
    __syncthreads();
    if (tid < 32) {
        float v = b_lin2[tid];
        for (int j = 0; j < 32; ++j) v += xsum[j]*W_lin2[j*32 + tid];
        x5[tid] = fmaxf(v, 0.f);
    }
    __syncthreads();
    if (tid < 10) {
        float v = b_lin3[tid];
        for (int j = 0; j < 32; ++j) v += x5[j]*W_lin3[j*10 + tid];
        lgs[tid] = v;
    }
    __syncthreads();
    if (tid < 10) {
        float mx = -1e30f;
        for (int t = 0; t < 10; ++t) mx = fmaxf(mx, lgs[t]);
        float sum = 0.f;
        for (int t = 0; t < 10; ++t) sum += expf(lgs[t] - mx);
        outp[b*10 + tid] = lgs[tid] - mx - logf(sum);
    }
    // ---- last-block fold of old k_f2 (counter slot 1035 zeroed by k_a) ----
    __syncthreads();
    if (tid == 0) {
        __threadfence();
        float old = atomicAdd(accp(xb,0,1035), 1.f);
        isLast = (old > 14.5f) ? 1 : 0;
    }
    __syncthreads();
    if (isLast && tid < 64) {
        __threadfence();
        int b2 = tid & 15, which = tid >> 4;
        float v = __hip_atomic_load(accp(xb,b2,1030 + which),
                                    __ATOMIC_RELAXED, __HIP_MEMORY_SCOPE_AGENT);
        for (int off = 1; off < 16; off <<= 1) v += __shfl_xor(v, off);
        float ct = __shfl(v, 0);
        float o1 = __shfl(v, 16);
        float mc = __shfl(v, 32);
        float o2 = __shfl(v, 48);
        if (tid == 0) {
            outp[160] = ct/16.f + sqrtf(fmaxf(o1, 0.f));
            outp[161] = mc/16.f + o2/16.f;
        }
    }
}

extern "C" void kernel_launch(void* const* d_in, const int* in_sizes, int n_in,
                              void* d_out, int out_size, void* d_ws, size_t ws_size,
                              hipStream_t stream)
{
    float* xb        = (float*)d_in[0];   // x, reused as scratch (restored by harness)
    const float* adj = (const float*)d_in[1];   // READ-ONLY
    const float* W_lin1 = (const float*)d_in[3];
    const float* b_lin1 = (const float*)d_in[4];
    const float* W_pool1= (const float*)d_in[5];
    const float* b_pool1= (const float*)d_in[6];
    const float* W_pool2= (const float*)d_in[7];
    const float* b_pool2= (const float*)d_in[8];
    const float* Wrel1  = (const float*)d_in[9];
    const float* brel1  = (const float*)d_in[10];
    const float* Wroot1 = (const float*)d_in[11];
    const float* Wrel2  = (const float*)d_in[12];
    const float* brel2  = (const float*)d_in[13];
    const float* Wroot2 = (const float*)d_in[14];
    const float* W_lin2 = (const float*)d_in[15];
    const float* b_lin2 = (const float*)d_in[16];
    const float* W_lin3 = (const float*)d_in[17];
    const float* b_lin3 = (const float*)d_in[18];
    u32* anb = (u32*)d_ws;   // 32 MB, fully overwritten by k_c
    (void)ws_size; (void)in_sizes; (void)n_in; (void)out_size;

    k_a<<<dim3(1024),      dim3(256), 0, stream>>>(xb, W_lin1, b_lin1, W_pool1, b_pool1);
    k_c<<<dim3(8,16,16),   dim3(256), 0, stream>>>(adj, xb, anb);
    k_y<<<dim3(16,16),     dim3(256), 0, stream>>>(anb, xb);
    k_d2<<<dim3(32,16),    dim3(256), 0, stream>>>(xb, Wrel1, brel1, Wroot1,
                                                   W_pool2, b_pool2);
    k_e<<<dim3(8,16,16),   dim3(256), 0, stream>>>(anb, xb);
    k_f1<<<dim3(16),       dim3(256), 0, stream>>>(xb, Wrel2, brel2, Wroot2,
                                                   W_lin2, b_lin2, W_lin3, b_lin3,
                                                   (float*)d_out);
}